// Round 4
// baseline (966.233 us; speedup 1.0000x reference)
//
#include <hip/hip_runtime.h>
#include <math.h>

#define NTOK   4096
#define DM     1024
#define NHEAD  16
#define HDIM   64
#define NEXP   8
#define CAP    1024
#define HID    2730
#define NFF2   5460
#define HIDP   2752   // HID padded to multiple of 32
#define KCD    86     // HIDP/32

typedef __attribute__((ext_vector_type(8))) short bf16x8;
typedef __attribute__((ext_vector_type(4))) float f32x4;
typedef __attribute__((ext_vector_type(8))) _Float16 h16x8;
typedef __attribute__((ext_vector_type(4))) _Float16 h16x4;
typedef __attribute__((ext_vector_type(8))) unsigned short u16x8;

__device__ __forceinline__ unsigned short f2bf(float f) {
  unsigned int u = __float_as_uint(f);
  u += 0x7fffu + ((u >> 16) & 1u);
  return (unsigned short)(u >> 16);
}

// async global->LDS, 16B per lane; LDS dest is wave-uniform base + lane*16
__device__ __forceinline__ void gll16(const void* g, void* l) {
  __builtin_amdgcn_global_load_lds((const __attribute__((address_space(1))) void*)g,
                                   (__attribute__((address_space(3))) void*)l, 16, 0, 0);
}

// ============== pack dense weights -> bf16 k-major tiles: chunk idx = (k-oct)*64+col = tid ======
__global__ __launch_bounds__(256) void pack_dense3(const float* __restrict__ q_w,
                                                   const float* __restrict__ ka_w,
                                                   const float* __restrict__ va_w,
                                                   const float* __restrict__ proj_w,
                                                   unsigned short* __restrict__ Wqt,
                                                   unsigned short* __restrict__ Wlatt,
                                                   unsigned short* __restrict__ Wprojt) {
  int b = blockIdx.x;
  int tid = threadIdx.x;
  int col = tid & 63;
  int k0 = (tid >> 6) * 8;
  int which = b >> 9;
  int bb = b & 511;
  int nt = bb >> 5, kc = bb & 31;
  int d0 = kc * 32 + k0;
  u16x8 o;
  if (which == 0) {
    const float* src = q_w + ((size_t)nt * 1024 + d0) * 64 + col;
#pragma unroll
    for (int j = 0; j < 8; j++) o[j] = f2bf(src[(size_t)j * 64]);
    *(u16x8*)(Wqt + (size_t)bb * 2048 + tid * 8) = o;
  } else if (which == 1) {
    int n = nt * 64 + col;
    const float* base;
    int h, l;
    if (n < 512) { h = n >> 5; l = n & 31; base = ka_w; }
    else { int m = n - 512; h = m >> 5; l = m & 31; base = va_w; }
    const float* src = base + ((size_t)h * 1024 + d0) * 32 + l;
#pragma unroll
    for (int j = 0; j < 8; j++) o[j] = f2bf(src[(size_t)j * 32]);
    *(u16x8*)(Wlatt + (size_t)bb * 2048 + tid * 8) = o;
  } else {
    int n = nt * 64 + col;
    const float* src = proj_w + (size_t)d0 * 1024 + n;
#pragma unroll
    for (int j = 0; j < 8; j++) o[j] = f2bf(src[(size_t)j * 1024]);
    *(u16x8*)(Wprojt + (size_t)bb * 2048 + tid * 8) = o;
  }
}

// ============== pack swiglu_w -> bf16 k-major tiles ==============
__global__ __launch_bounds__(256) void pack_swiglu(const float* __restrict__ swiglu_w,
                                                   unsigned short* __restrict__ Wpk) {
  int b = blockIdx.x;            // = (e*43 + jt)*32 + kc32
  int kc32 = b & 31;
  int ejt = b >> 5;
  int jt = ejt % 43;
  int e = ejt / 43;
  int tid = threadIdx.x;
  int col = tid & 63;
  int k0 = (tid >> 6) * 8;
  int n = jt * 64 + col;
  bool nv = n < HID;
  const float* src = swiglu_w + ((size_t)e * DM + kc32 * 32 + k0) * NFF2 + n;
  u16x8 o1, o2;
#pragma unroll
  for (int j = 0; j < 8; j++) {
    float v1 = nv ? src[(size_t)j * NFF2] : 0.f;
    float v2 = nv ? src[(size_t)j * NFF2 + HID] : 0.f;
    o1[j] = f2bf(v1);
    o2[j] = f2bf(v2);
  }
  unsigned short* dst = Wpk + (size_t)b * 4096 + tid * 8;
  *(u16x8*)dst = o1;
  *(u16x8*)(dst + 2048) = o2;
}

// ============== pack down_w -> bf16 k-major tiles, zero-pad k>=HID ======
__global__ __launch_bounds__(256) void pack_down(const float* __restrict__ down_w,
                                                 unsigned short* __restrict__ Wdk) {
  int b = blockIdx.x;            // (e*16+nt)*86 + kci
  int kci = b % KCD;
  int ent = b / KCD;
  int nt = ent & 15;
  int e = ent >> 4;
  int tid = threadIdx.x;
  int col = tid & 63, k0 = (tid >> 6) * 8;
  int n = nt * 64 + col;
  int kbase = kci * 32 + k0;
  const float* src = down_w + ((size_t)e * HID + kbase) * DM + n;
  u16x8 o;
#pragma unroll
  for (int j = 0; j < 8; j++) {
    float v = (kbase + j < HID) ? src[(size_t)j * DM] : 0.f;
    o[j] = f2bf(v);
  }
  *(u16x8*)(Wdk + (size_t)b * 2048 + tid * 8) = o;
}

// ============================ RMSNorm (bf16 out; optional fp32 out) ============================
template <bool F32OUT>
__global__ __launch_bounds__(256) void rms_kernel(const float* __restrict__ x,
                                                  const float* __restrict__ w,
                                                  float* __restrict__ out,
                                                  unsigned short* __restrict__ outb) {
  int row = blockIdx.x;
  int tid = threadIdx.x;
  const float4 v = ((const float4*)(x + (size_t)row * DM))[tid];
  float ss = v.x * v.x + v.y * v.y + v.z * v.z + v.w * v.w;
#pragma unroll
  for (int off = 32; off >= 1; off >>= 1) ss += __shfl_down(ss, off);
  __shared__ float red[4];
  if ((tid & 63) == 0) red[tid >> 6] = ss;
  __syncthreads();
  float tot = red[0] + red[1] + red[2] + red[3];
  float scale = rsqrtf(tot * (1.0f / 1024.0f) + 1e-5f);
  const float4 wv = ((const float4*)w)[tid];
  float4 o;
  o.x = v.x * scale * wv.x; o.y = v.y * scale * wv.y;
  o.z = v.z * scale * wv.z; o.w = v.w * scale * wv.w;
  if (F32OUT) ((float4*)(out + (size_t)row * DM))[tid] = o;
  ushort4 ob;
  ob.x = f2bf(o.x); ob.y = f2bf(o.y); ob.z = f2bf(o.z); ob.w = f2bf(o.w);
  *(ushort4*)(outb + (size_t)row * DM + tid * 4) = ob;
}

// ============================ dense bf16 MFMA GEMM (global_load_lds staging) ============================
// C[M,N] = A[M,K]@B[K,N] (+bias)(+res). BK=32, k-major linear LDS tiles, 1 barrier/K-step.
template <bool BIAS, bool RES>
__global__ __launch_bounds__(256) void mfma_dense(const unsigned short* __restrict__ A,
                                                  const unsigned short* __restrict__ Bpk,
                                                  const float* __restrict__ bias,
                                                  const float* __restrict__ res,
                                                  float* __restrict__ C, int K, int N) {
  int m0 = blockIdx.x * 128;
  int n0 = blockIdx.y * 128;
  int KC = K >> 5;
  __shared__ unsigned short Asl[2][4096];   // 128 rows x 32k, chunk = lq*128+row
  __shared__ unsigned short Bsl[2][4096];   // 2 subtiles of 64col x 32k, chunk = sub*256+lq*64+col
  int tid = threadIdx.x;
  int l6 = tid & 63, wid = tid >> 6;
  int lr = l6 & 15, lq = l6 >> 4;
  int wm0 = (wid >> 1) * 64, wn0 = (wid & 1) * 64;
  int aw = wid * 512;    // wave's 1KB staging window (shorts)
  f32x4 c[4][4];
  f32x4 zz = {0.f, 0.f, 0.f, 0.f};
#pragma unroll
  for (int i = 0; i < 4; i++)
#pragma unroll
    for (int j = 0; j < 4; j++) c[i][j] = zz;
  const unsigned short* aAg = A + (size_t)(m0 + (tid & 127)) * K + (tid >> 7) * 8;
  const unsigned short* bg0 = Bpk + (size_t)((n0 >> 6) * KC) * 2048 + tid * 8;
  const unsigned short* bg1 = Bpk + (size_t)(((n0 >> 6) + 1) * KC) * 2048 + tid * 8;
#define DEN_STG(cur, kci)                                       \
  {                                                             \
    gll16(aAg + (kci) * 32, &Asl[cur][aw]);                     \
    gll16(aAg + (kci) * 32 + 16, &Asl[cur][2048 + aw]);         \
    gll16(bg0 + (size_t)(kci) * 2048, &Bsl[cur][aw]);           \
    gll16(bg1 + (size_t)(kci) * 2048, &Bsl[cur][2048 + aw]);    \
  }
  DEN_STG(0, 0);
  __syncthreads();
  for (int kci = 0; kci < KC; kci++) {
    int cur = kci & 1;
    if (kci + 1 < KC) DEN_STG(cur ^ 1, kci + 1);
    bf16x8 a[4], b[4];
#pragma unroll
    for (int mi = 0; mi < 4; mi++)
      a[mi] = *(bf16x8*)&Asl[cur][(lq * 128 + wm0 + mi * 16 + lr) * 8];
#pragma unroll
    for (int ni = 0; ni < 4; ni++)
      b[ni] = *(bf16x8*)&Bsl[cur][((wn0 >> 6) * 256 + lq * 64 + ni * 16 + lr) * 8];
#pragma unroll
    for (int mi = 0; mi < 4; mi++)
#pragma unroll
      for (int ni = 0; ni < 4; ni++)
        c[mi][ni] = __builtin_amdgcn_mfma_f32_16x16x32_bf16(a[mi], b[ni], c[mi][ni], 0, 0, 0);
    __syncthreads();
  }
#undef DEN_STG
#pragma unroll
  for (int mi = 0; mi < 4; mi++)
#pragma unroll
    for (int ni = 0; ni < 4; ni++) {
      int nn = n0 + wn0 + ni * 16 + lr;
      float bv = BIAS ? bias[nn] : 0.f;
#pragma unroll
      for (int r = 0; r < 4; r++) {
        int mm = m0 + wm0 + mi * 16 + lq * 4 + r;
        float v = c[mi][ni][r] + bv;
        if (RES) v += res[(size_t)mm * N + nn];
        C[(size_t)mm * N + nn] = v;
      }
    }
}

// ============================ latent -> K,V expand (V out f16) ============================
__global__ void expand_kernel(const float* __restrict__ latents, const float* __restrict__ kb_w,
                              const float* __restrict__ vb_w, float* __restrict__ kpre,
                              _Float16* __restrict__ vf) {
  int idx = blockIdx.x * 256 + threadIdx.x;  // 4M
  int e = idx & 63;
  int t = (idx >> 6) & 1023;
  int h = (idx >> 16) & 15;
  int b = idx >> 20;
  const float* lrow = latents + ((size_t)(b * 1024 + t)) * DM;
  const float* kb = kb_w + (size_t)h * 2048;
  const float* vb = vb_w + (size_t)h * 2048;
  float ka = 0.f, va = 0.f;
#pragma unroll
  for (int l = 0; l < 32; l++) {
    ka += lrow[h * 32 + l] * kb[l * 64 + e];
    va += lrow[512 + h * 32 + l] * vb[l * 64 + e];
  }
  kpre[idx] = ka;
  vf[idx] = (_Float16)va;
}

// ============================ RoPE (out f16) ============================
template <bool IN_BTHD>
__global__ void rope_kernel(const float* __restrict__ in, _Float16* __restrict__ out) {
  int idx = blockIdx.x * 256 + threadIdx.x;  // 2M
  int i = idx & 31;
  int t = (idx >> 5) & 1023;
  int h = (idx >> 15) & 15;
  int b = idx >> 19;
  size_t ib;
  if (IN_BTHD)
    ib = ((size_t)(b * 1024 + t)) * DM + h * 64;
  else
    ib = ((size_t)((b * 16 + h) * 1024 + t)) * 64;
  float t1 = in[ib + 2 * i], t2 = in[ib + 2 * i + 1];
  float inv = exp2f(-(float)i * 0.41524101186091903f);  // 10000^(-i/32)
  float ang = (float)t * inv;
  float s, c;
  sincosf(ang, &s, &c);
  size_t ob = ((size_t)((b * 16 + h) * 1024 + t)) * 64;
  out[ob + i] = (_Float16)(t1 * c - t2 * s);
  out[ob + 32 + i] = (_Float16)(t1 * s + t2 * c);
}

// ============================ flash attention (f16 MFMA, bf16 out) ============================
__global__ __launch_bounds__(256) void attn_mfma(const _Float16* __restrict__ qf,
                                                 const _Float16* __restrict__ kf,
                                                 const _Float16* __restrict__ vf,
                                                 unsigned short* __restrict__ o) {
  __shared__ _Float16 Ks[64][72];
  __shared__ _Float16 Vt[64][68];
  int bh = blockIdx.y;
  int q0 = blockIdx.x * 64;
  int tid = threadIdx.x;
  int wv = tid >> 6, lane = tid & 63;
  int lr = lane & 15, lq = lane >> 4;
  const size_t base = (size_t)bh * 1024 * 64;
  const _Float16* qrow = qf + base + (size_t)(q0 + wv * 16 + lr) * 64;
  h16x8 qfr[2];
  qfr[0] = *(const h16x8*)(qrow + lq * 8);
  qfr[1] = *(const h16x8*)(qrow + 32 + lq * 8);
  float mrow = -3.0e38f, lsum = 0.f;
  f32x4 oacc[4];
  f32x4 zz = {0.f, 0.f, 0.f, 0.f};
#pragma unroll
  for (int i = 0; i < 4; i++) oacc[i] = zz;
  int skey = tid >> 2, spart = tid & 3;
  int vkey = tid & 63, vdb = (tid >> 6) * 16;

  for (int kt = 0; kt < 16; kt++) {
    __syncthreads();
    {
      const _Float16* kg = kf + base + (size_t)(kt * 64 + skey) * 64 + spart * 16;
      *(h16x8*)&Ks[skey][spart * 16] = *(const h16x8*)kg;
      *(h16x8*)&Ks[skey][spart * 16 + 8] = *(const h16x8*)(kg + 8);
      const _Float16* vg = vf + base + (size_t)(kt * 64 + vkey) * 64 + vdb;
      h16x8 v0 = *(const h16x8*)vg;
      h16x8 v1 = *(const h16x8*)(vg + 8);
#pragma unroll
      for (int j = 0; j < 8; j++) {
        Vt[vdb + j][vkey] = v0[j];
        Vt[vdb + 8 + j][vkey] = v1[j];
      }
    }
    __syncthreads();
    f32x4 st[4];
#pragma unroll
    for (int ni = 0; ni < 4; ni++) {
      st[ni] = zz;
#pragma unroll
      for (int kc = 0; kc < 2; kc++) {
        h16x8 ak = *(const h16x8*)&Ks[ni * 16 + lr][kc * 32 + lq * 8];
        st[ni] = __builtin_amdgcn_mfma_f32_16x16x32_f16(ak, qfr[kc], st[ni], 0, 0, 0);
      }
    }
    float smax = -3.0e38f;
#pragma unroll
    for (int ni = 0; ni < 4; ni++)
#pragma unroll
      for (int r = 0; r < 4; r++) {
        st[ni][r] *= 0.125f;
        smax = fmaxf(smax, st[ni][r]);
      }
    smax = fmaxf(smax, __shfl_xor(smax, 16));
    smax = fmaxf(smax, __shfl_xor(smax, 32));
    float newm = fmaxf(mrow, smax);
    float alpha = expf(mrow - newm);
    float rsum = 0.f;
    h16x4 pf[4];
#pragma unroll
    for (int ni = 0; ni < 4; ni++)
#pragma unroll
      for (int r = 0; r < 4; r++) {
        float p = expf(st[ni][r] - newm);
        rsum += p;
        pf[ni][r] = (_Float16)p;
      }
    rsum += __shfl_xor(rsum, 16);
    rsum += __shfl_xor(rsum, 32);
    lsum = lsum * alpha + rsum;
    mrow = newm;
#pragma unroll
    for (int dt = 0; dt < 4; dt++) {
      oacc[dt][0] *= alpha; oacc[dt][1] *= alpha;
      oacc[dt][2] *= alpha; oacc[dt][3] *= alpha;
    }
#pragma unroll
    for (int dt = 0; dt < 4; dt++)
#pragma unroll
      for (int ni = 0; ni < 4; ni++) {
        h16x4 va = *(const h16x4*)&Vt[dt * 16 + lr][ni * 16 + lq * 4];
        oacc[dt] = __builtin_amdgcn_mfma_f32_16x16x16f16(va, pf[ni], oacc[dt], 0, 0, 0);
      }
  }
  int b = bh >> 4, h = bh & 15;
  int qg = q0 + wv * 16 + lr;
  float invl = 1.0f / lsum;
  unsigned short* orow = o + (size_t)(b * 1024 + qg) * DM + h * 64;
#pragma unroll
  for (int dt = 0; dt < 4; dt++) {
    ushort4 ov;
    ov.x = f2bf(oacc[dt][0] * invl);
    ov.y = f2bf(oacc[dt][1] * invl);
    ov.z = f2bf(oacc[dt][2] * invl);
    ov.w = f2bf(oacc[dt][3] * invl);
    *(ushort4*)(orow + dt * 16 + lq * 4) = ov;
  }
}

// ============================ router ============================
__global__ __launch_bounds__(256) void router_kernel(
    const float* __restrict__ xn2, const float* __restrict__ route_w,
    const float* __restrict__ route_b, const float* __restrict__ noise_w,
    const float* __restrict__ noise_b, const float* __restrict__ noise_eps,
    int* __restrict__ topi, float* __restrict__ flat_p, float* __restrict__ probsum,
    int* __restrict__ slotmap) {
  int wave = threadIdx.x >> 6;
  int lane = threadIdx.x & 63;
  int tk = blockIdx.x * 4 + wave;
  float acc[8] = {0.f}, nacc[8] = {0.f};
  const float* xr = xn2 + (size_t)tk * DM;
  for (int it = 0; it < 16; it++) {
    int d = it * 64 + lane;
    float xv = xr[d];
    const float* rw = route_w + d * 8;
    const float* nw = noise_w + d * 8;
#pragma unroll
    for (int e = 0; e < 8; e++) {
      acc[e] += xv * rw[e];
      nacc[e] += xv * nw[e];
    }
  }
#pragma unroll
  for (int off = 32; off >= 1; off >>= 1) {
#pragma unroll
    for (int e = 0; e < 8; e++) {
      acc[e] += __shfl_down(acc[e], off);
      nacc[e] += __shfl_down(nacc[e], off);
    }
  }
  if (lane == 0) {
    float noisy[8];
#pragma unroll
    for (int e = 0; e < 8; e++) {
      float lg = acc[e] + route_b[e];
      float nl = nacc[e] + noise_b[e];
      float sp = (nl > 20.f) ? nl : log1pf(expf(nl));
      noisy[e] = lg + noise_eps[tk * 8 + e] * sp;
    }
    int i1 = 0;
    float n1 = noisy[0];
#pragma unroll
    for (int e = 1; e < 8; e++)
      if (noisy[e] > n1) { n1 = noisy[e]; i1 = e; }
    int i2 = -1;
    float n2 = -3.0e38f;
#pragma unroll
    for (int e = 0; e < 8; e++)
      if (e != i1 && noisy[e] > n2) { n2 = noisy[e]; i2 = e; }
    float r = expf(n2 - n1);
    float p1 = 1.0f / (1.0f + r);
    float p2 = r / (1.0f + r);
    topi[tk * 2] = i1;
    topi[tk * 2 + 1] = i2;
#pragma unroll
    for (int e = 0; e < 8; e++) flat_p[tk * 8 + e] = (e == i1) ? p1 : ((e == i2) ? p2 : 0.f);
    atomicAdd(&probsum[i1], p1);
    atomicAdd(&probsum[i2], p2);
    slotmap[tk * 2] = -1;
    slotmap[tk * 2 + 1] = -1;
  }
}

// ============================ capacity scan ============================
__global__ __launch_bounds__(512) void scan_kernel(const int* __restrict__ topi,
                                                   const float* __restrict__ flat_p,
                                                   int* __restrict__ tok, float* __restrict__ gate,
                                                   int* __restrict__ cnt, int* __restrict__ slotmap) {
  int e = threadIdx.x >> 6;
  int lane = threadIdx.x & 63;
  int count = 0;
  for (int base = 0; base < NTOK; base += 64) {
    int t = base + lane;
    int a = topi[t * 2], b = topi[t * 2 + 1];
    bool mflag = (a == e) || (b == e);
    unsigned long long mask = __ballot(mflag);
    int pos = count + __popcll(mask & ((1ull << lane) - 1ull));
    if (mflag && pos < CAP) {
      tok[e * CAP + pos] = t;
      gate[e * CAP + pos] = flat_p[t * 8 + e];
      int k = (a == e) ? 0 : 1;
      slotmap[t * 2 + k] = pos;
    }
    count += __popcll(mask);
  }
  if (lane == 0) cnt[e] = (count < CAP) ? count : CAP;
}

// ============================ expert GEMM 1: gathered xn2b @ Wpk, fused SiLU ============================
// XCD-pinned: e = L&7. global_load_lds staging (per-lane gather on A source), 1 barrier/K-step.
__global__ __launch_bounds__(256) void mfma_swiglu(const unsigned short* __restrict__ xn2b,
                                                   const unsigned short* __restrict__ Wpk,
                                                   const int* __restrict__ tok,
                                                   const int* __restrict__ cnt,
                                                   unsigned short* __restrict__ ACT) {
  int L = blockIdx.x;
  int e = L & 7;
  int gw = L >> 3;
  int m0 = (gw & 7) * 128;
  int jt = gw >> 3;
  int j0 = jt * 64;
  __shared__ unsigned short Asl[2][4096];   // 128 x 32k
  __shared__ unsigned short B1sl[2][2048];  // 64 x 32k
  __shared__ unsigned short B2sl[2][2048];
  int tid = threadIdx.x;
  int l6 = tid & 63, wid = tid >> 6;
  int lr = l6 & 15, lq = l6 >> 4;
  int wm0 = (wid >> 1) * 64, wn0 = (wid & 1) * 32;
  int aw = wid * 512;
  int ce = cnt[e];
  int slot = m0 + (tid & 127);
  int tr = (slot < ce) ? tok[e * CAP + slot] : 0;
  const unsigned short* aAg = xn2b + (size_t)tr * DM + (tid >> 7) * 8;
  const unsigned short* wg = Wpk + (size_t)(e * 43 + jt) * 32 * 4096 + tid * 8;
  f32x4 c1[4][2], c2[4][2];
  f32x4 zz = {0.f, 0.f, 0.f, 0.f};
#pragma unroll
  for (int i = 0; i < 4; i++)
#pragma unroll
    for (int j = 0; j < 2; j++) { c1[i][j] = zz; c2[i][j] = zz; }
#define SWG_STG(cur, kci)                                        \
  {                                                              \
    gll16(aAg + (kci) * 32, &Asl[cur][aw]);                      \
    gll16(aAg + (kci) * 32 + 16, &Asl[cur][2048 + aw]);          \
    gll16(wg + (size_t)(kci) * 4096, &B1sl[cur][aw]);            \
    gll16(wg + (size_t)(kci) * 4096 + 2048, &B2sl[cur][aw]);     \
  }
  SWG_STG(0, 0);
  __syncthreads();
  for (int kci = 0; kci < 32; kci++) {
    int cur = kci & 1;
    if (kci + 1 < 32) SWG_STG(cur ^ 1, kci + 1);
    bf16x8 a[4], b1[2], b2[2];
#pragma unroll
    for (int mi = 0; mi < 4; mi++)
      a[mi] = *(bf16x8*)&Asl[cur][(lq * 128 + wm0 + mi * 16 + lr) * 8];
#pragma unroll
    for (int ni = 0; ni < 2; ni++) {
      b1[ni] = *(bf16x8*)&B1sl[cur][(lq * 64 + wn0 + ni * 16 + lr) * 8];
      b2[ni] = *(bf16x8*)&B2sl[cur][(lq * 64 + wn0 + ni * 16 + lr) * 8];
    }
#pragma unroll
    for (int mi = 0; mi < 4; mi++)
#pragma unroll
      for (int ni = 0; ni < 2; ni++) {
        c1[mi][ni] = __builtin_amdgcn_mfma_f32_16x16x32_bf16(a[mi], b1[ni], c1[mi][ni], 0, 0, 0);
        c2[mi][ni] = __builtin_amdgcn_mfma_f32_16x16x32_bf16(a[mi], b2[ni], c2[mi][ni], 0, 0, 0);
      }
    __syncthreads();
  }
#undef SWG_STG
#pragma unroll
  for (int mi = 0; mi < 4; mi++)
#pragma unroll
    for (int ni = 0; ni < 2; ni++)
#pragma unroll
      for (int r = 0; r < 4; r++) {
        int mm = m0 + wm0 + mi * 16 + lq * 4 + r;
        int cc = j0 + wn0 + ni * 16 + lr;
        float h1 = c1[mi][ni][r], h2 = c2[mi][ni][r];
        float act = (h1 / (1.0f + expf(-h1))) * h2;
        ACT[(size_t)e * CAP * HIDP + (size_t)mm * HIDP + cc] = f2bf(act);
      }
}

// ============================ expert GEMM 2: ACT @ Wdk -> OE fp32 ============================
// XCD-pinned by expert (e = L&7). global_load_lds staging, 1 barrier/K-step.
__global__ __launch_bounds__(256) void mfma_down(const unsigned short* __restrict__ ACT,
                                                 const unsigned short* __restrict__ Wdk,
                                                 float* __restrict__ OE) {
  int L = blockIdx.x;
  int e = L & 7;
  int gw = L >> 3;
  int m0 = (gw & 7) * 128;
  int nt0 = (gw >> 3) * 2;
  int n0 = nt0 * 64;
  __shared__ unsigned short Asl[2][4096];
  __shared__ unsigned short Bsl[2][4096];
  int tid = threadIdx.x;
  int l6 = tid & 63, wid = tid >> 6;
  int lr = l6 & 15, lq = l6 >> 4;
  int wm0 = (wid >> 1) * 64, wn0 = (wid & 1) * 64;
  int aw = wid * 512;
  f32x4 c[4][4];
  f32x4 zz = {0.f, 0.f, 0.f, 0.f};
#pragma unroll
  for (int i = 0; i < 4; i++)
#pragma unroll
    for (int j = 0; j < 4; j++) c[i][j] = zz;
  const unsigned short* aAg =
      ACT + (size_t)e * CAP * HIDP + (size_t)(m0 + (tid & 127)) * HIDP + (tid >> 7) * 8;
  const unsigned short* bg0 = Wdk + ((size_t)(e * 16 + nt0) * KCD) * 2048 + tid * 8;
  const unsigned short* bg1 = Wdk + ((size_t)(e * 16 + nt0 + 1) * KCD) * 2048 + tid * 8;
#define DWN_STG(cur, kci)                                       \
  {                                                             \
    gll16(aAg + (kci) * 32, &Asl[cur][aw]);                     \
    gll16(aAg + (kci) * 32 + 16, &Asl[cur][2048 + aw]);         \
    gll16(bg0 + (size_t)(kci) * 2048, &Bsl[cur][aw]);           \
    gll16(bg1 + (size_t)(kci) * 2048, &Bsl[cur][2048 + aw]);    \
  }
  DWN_STG(0, 0);
  __syncthreads();
  for (int kci = 0; kci < KCD; kci++) {
    int cur = kci & 1;
    if (kci + 1 < KCD) DWN_STG(cur ^ 1, kci + 1);
    bf16x8 a[4], b[4];
#pragma unroll
    for (int mi = 0; mi < 4; mi++)
      a[mi] = *(bf16x8*)&Asl[cur][(lq * 128 + wm0 + mi * 16 + lr) * 8];
#pragma unroll
    for (int ni = 0; ni < 4; ni++)
      b[ni] = *(bf16x8*)&Bsl[cur][((wn0 >> 6) * 256 + lq * 64 + ni * 16 + lr) * 8];
#pragma unroll
    for (int mi = 0; mi < 4; mi++)
#pragma unroll
      for (int ni = 0; ni < 4; ni++)
        c[mi][ni] = __builtin_amdgcn_mfma_f32_16x16x32_bf16(a[mi], b[ni], c[mi][ni], 0, 0, 0);
    __syncthreads();
  }
#undef DWN_STG
#pragma unroll
  for (int mi = 0; mi < 4; mi++)
#pragma unroll
    for (int ni = 0; ni < 4; ni++)
#pragma unroll
      for (int r = 0; r < 4; r++) {
        int mm = m0 + wm0 + mi * 16 + lq * 4 + r;
        int nn = n0 + wn0 + ni * 16 + lr;
        OE[((size_t)e << 20) + (size_t)mm * DM + nn] = c[mi][ni][r];
      }
}

// ============================ combine ============================
__global__ void combine_kernel(const float* __restrict__ x2, const float* __restrict__ OE,
                               const int* __restrict__ topi, const int* __restrict__ slotmap,
                               const float* __restrict__ flat_p, float* __restrict__ out) {
  int idx = blockIdx.x * 256 + threadIdx.x;  // 1M float4s
  int t = idx >> 8;
  int c4 = (idx & 255) * 4;
  float4 v = *(const float4*)(x2 + (size_t)t * DM + c4);
#pragma unroll
  for (int k = 0; k < 2; k++) {
    int s = slotmap[t * 2 + k];
    if (s >= 0) {
      int e = topi[t * 2 + k];
      float g = flat_p[t * 8 + e];
      float4 ov = *(const float4*)(OE + ((size_t)e << 20) + (size_t)s * DM + c4);
      v.x += g * ov.x; v.y += g * ov.y; v.z += g * ov.z; v.w += g * ov.w;
    }
  }
  *(float4*)(out + (size_t)t * DM + c4) = v;
}

__global__ void aux_kernel(const float* __restrict__ probsum, float* __restrict__ out) {
  if (threadIdx.x == 0) {
    float s = 0.f;
#pragma unroll
    for (int e = 0; e < 8; e++) {
      float d = probsum[e] * (1.0f / 4096.0f) - 0.125f;
      s += d * d;
    }
    out[4194304] = s;
  }
}

// ============================ launch ============================
extern "C" void kernel_launch(void* const* d_in, const int* in_sizes, int n_in, void* d_out,
                              int out_size, void* d_ws, size_t ws_size, hipStream_t stream) {
  const float* x = (const float*)d_in[0];
  const float* noise_eps = (const float*)d_in[1];
  const float* ln1_w = (const float*)d_in[2];
  const float* ln2_w = (const float*)d_in[3];
  const float* q_w = (const float*)d_in[4];
  const float* q_b = (const float*)d_in[5];
  const float* ka_w = (const float*)d_in[6];
  const float* kb_w = (const float*)d_in[7];
  const float* va_w = (const float*)d_in[8];
  const float* vb_w = (const float*)d_in[9];
  const float* proj_w = (const float*)d_in[10];
  const float* proj_b = (const float*)d_in[11];
  const float* route_w = (const float*)d_in[12];
  const float* route_b = (const float*)d_in[13];
  const float* noise_w = (const float*)d_in[14];
  const float* noise_b = (const float*)d_in[15];
  const float* swiglu_w = (const float*)d_in[16];
  const float* down_w = (const float*)d_in[17];
  float* out = (float*)d_out;
  char* w = (char*)d_ws;
  const size_t MB = 1ull << 20;

  // ---- memory map (MiB), peak 171 ----
  // persistent: x2 [0,16) | xn2 [16,32) | xn2b [32,40) | sm [40,41)
  // phase A:   xnb [42,50) qtmp [50,66) latents [66,82) kpre [82,98) qfb [98,106)
  //            kfb [106,114) vfb [114,122) obb [122,130) Wqt [130,132) Wlatt [132,134) Wprojt [134,136)
  // after proj: Wpk [42,128)  (overlays dead phase-A buffers)
  // expert:    ACT [128,171)
  // after swiglu: Wdk [42,85) | OE [86,118)
  float* x2 = (float*)(w + 0 * MB);
  float* xn2 = (float*)(w + 16 * MB);
  unsigned short* xn2b = (unsigned short*)(w + 32 * MB);
  char* sm = w + 40 * MB;
  unsigned short* xnb = (unsigned short*)(w + 42 * MB);
  float* qtmp = (float*)(w + 50 * MB);
  float* latents = (float*)(w + 66 * MB);
  float* kpre = (float*)(w + 82 * MB);
  _Float16* qfb = (_Float16*)(w + 98 * MB);
  _Float16* kfb = (_Float16*)(w + 106 * MB);
  _Float16* vfb = (_Float16*)(w + 114 * MB);
  unsigned short* obb = (unsigned short*)(w + 122 * MB);
  unsigned short* Wqt = (unsigned short*)(w + 130 * MB);
  unsigned short* Wlatt = (unsigned short*)(w + 132 * MB);
  unsigned short* Wprojt = (unsigned short*)(w + 134 * MB);
  unsigned short* Wpk = (unsigned short*)(w + 42 * MB);
  unsigned short* ACT = (unsigned short*)(w + 128 * MB);
  unsigned short* Wdk = (unsigned short*)(w + 42 * MB);
  float* OE = (float*)(w + 86 * MB);

  int* topi = (int*)sm;
  int* tok = (int*)(sm + 64 * 1024);
  int* cntb = (int*)(sm + 128 * 1024);
  int* slotmap = (int*)(sm + 192 * 1024);
  float* flat_p = (float*)(sm + 256 * 1024);
  float* gateb = (float*)(sm + 512 * 1024);
  float* probsum = (float*)(sm + 576 * 1024);

  pack_dense3<<<1536, 256, 0, stream>>>(q_w, ka_w, va_w, proj_w, Wqt, Wlatt, Wprojt);
  rms_kernel<false><<<4096, 256, 0, stream>>>(x, ln1_w, nullptr, xnb);
  mfma_dense<true, false><<<dim3(32, 8), 256, 0, stream>>>(xnb, Wqt, q_b, nullptr, qtmp, 1024, 1024);
  mfma_dense<false, false><<<dim3(32, 8), 256, 0, stream>>>(xnb, Wlatt, nullptr, nullptr, latents, 1024, 1024);
  expand_kernel<<<16384, 256, 0, stream>>>(latents, kb_w, vb_w, kpre, vfb);
  rope_kernel<true><<<8192, 256, 0, stream>>>(qtmp, qfb);
  rope_kernel<false><<<8192, 256, 0, stream>>>(kpre, kfb);
  attn_mfma<<<dim3(16, 64), 256, 0, stream>>>(qfb, kfb, vfb, obb);
  mfma_dense<true, true><<<dim3(32, 8), 256, 0, stream>>>(obb, Wprojt, proj_b, x, x2, 1024, 1024);
  pack_swiglu<<<11008, 256, 0, stream>>>(swiglu_w, Wpk);
  rms_kernel<true><<<4096, 256, 0, stream>>>(x2, ln2_w, xn2, xn2b);
  hipMemsetAsync(probsum, 0, 8 * sizeof(float), stream);
  router_kernel<<<1024, 256, 0, stream>>>(xn2, route_w, route_b, noise_w, noise_b, noise_eps,
                                          topi, flat_p, probsum, slotmap);
  scan_kernel<<<1, 512, 0, stream>>>(topi, flat_p, tok, gateb, cntb, slotmap);
  mfma_swiglu<<<2752, 256, 0, stream>>>(xn2b, Wpk, tok, cntb, ACT);
  pack_down<<<11008, 256, 0, stream>>>(down_w, Wdk);
  mfma_down<<<512, 256, 0, stream>>>(ACT, Wdk, OE);
  combine_kernel<<<4096, 256, 0, stream>>>(x2, OE, topi, slotmap, flat_p, out);
  aux_kernel<<<1, 64, 0, stream>>>(probsum, out);
}

// Round 5
// 922.671 us; speedup vs baseline: 1.0472x; 1.0472x over previous
//
#include <hip/hip_runtime.h>
#include <math.h>

#define NTOK   4096
#define DM     1024
#define NHEAD  16
#define HDIM   64
#define NEXP   8
#define CAP    1024
#define HID    2730
#define NFF2   5460
#define HIDP   2752   // HID padded to multiple of 32
#define KCD    86     // HIDP/32

typedef __attribute__((ext_vector_type(8))) short bf16x8;
typedef __attribute__((ext_vector_type(4))) float f32x4;
typedef __attribute__((ext_vector_type(8))) _Float16 h16x8;
typedef __attribute__((ext_vector_type(4))) _Float16 h16x4;
typedef __attribute__((ext_vector_type(8))) unsigned short u16x8;

__device__ __forceinline__ unsigned short f2bf(float f) {
  unsigned int u = __float_as_uint(f);
  u += 0x7fffu + ((u >> 16) & 1u);
  return (unsigned short)(u >> 16);
}

// async global->LDS, 16B per lane; LDS dest is wave-uniform base + lane*16
__device__ __forceinline__ void gll16(const void* g, void* l) {
  __builtin_amdgcn_global_load_lds((const __attribute__((address_space(1))) void*)g,
                                   (__attribute__((address_space(3))) void*)l, 16, 0, 0);
}

// counted-vmcnt sync point: never drain to 0 in the main loop (T4)
#define VM_WAIT4 asm volatile("s_waitcnt vmcnt(4)" ::: "memory")
#define VM_WAIT0 asm volatile("s_waitcnt vmcnt(0)" ::: "memory")
#define CFENCE   asm volatile("" ::: "memory")

// ============== pack dense weights -> bf16 k-major tiles: chunk idx = (k-oct)*64+col = tid ======
__global__ __launch_bounds__(256) void pack_dense3(const float* __restrict__ q_w,
                                                   const float* __restrict__ ka_w,
                                                   const float* __restrict__ va_w,
                                                   const float* __restrict__ proj_w,
                                                   unsigned short* __restrict__ Wqt,
                                                   unsigned short* __restrict__ Wlatt,
                                                   unsigned short* __restrict__ Wprojt) {
  int b = blockIdx.x;
  int tid = threadIdx.x;
  int col = tid & 63;
  int k0 = (tid >> 6) * 8;
  int which = b >> 9;
  int bb = b & 511;
  int nt = bb >> 5, kc = bb & 31;
  int d0 = kc * 32 + k0;
  u16x8 o;
  if (which == 0) {
    const float* src = q_w + ((size_t)nt * 1024 + d0) * 64 + col;
#pragma unroll
    for (int j = 0; j < 8; j++) o[j] = f2bf(src[(size_t)j * 64]);
    *(u16x8*)(Wqt + (size_t)bb * 2048 + tid * 8) = o;
  } else if (which == 1) {
    int n = nt * 64 + col;
    const float* base;
    int h, l;
    if (n < 512) { h = n >> 5; l = n & 31; base = ka_w; }
    else { int m = n - 512; h = m >> 5; l = m & 31; base = va_w; }
    const float* src = base + ((size_t)h * 1024 + d0) * 32 + l;
#pragma unroll
    for (int j = 0; j < 8; j++) o[j] = f2bf(src[(size_t)j * 32]);
    *(u16x8*)(Wlatt + (size_t)bb * 2048 + tid * 8) = o;
  } else {
    int n = nt * 64 + col;
    const float* src = proj_w + (size_t)d0 * 1024 + n;
#pragma unroll
    for (int j = 0; j < 8; j++) o[j] = f2bf(src[(size_t)j * 1024]);
    *(u16x8*)(Wprojt + (size_t)bb * 2048 + tid * 8) = o;
  }
}

// ============== pack swiglu_w -> bf16 k-major tiles ==============
__global__ __launch_bounds__(256) void pack_swiglu(const float* __restrict__ swiglu_w,
                                                   unsigned short* __restrict__ Wpk) {
  int b = blockIdx.x;            // = (e*43 + jt)*32 + kc32
  int kc32 = b & 31;
  int ejt = b >> 5;
  int jt = ejt % 43;
  int e = ejt / 43;
  int tid = threadIdx.x;
  int col = tid & 63;
  int k0 = (tid >> 6) * 8;
  int n = jt * 64 + col;
  bool nv = n < HID;
  const float* src = swiglu_w + ((size_t)e * DM + kc32 * 32 + k0) * NFF2 + n;
  u16x8 o1, o2;
#pragma unroll
  for (int j = 0; j < 8; j++) {
    float v1 = nv ? src[(size_t)j * NFF2] : 0.f;
    float v2 = nv ? src[(size_t)j * NFF2 + HID] : 0.f;
    o1[j] = f2bf(v1);
    o2[j] = f2bf(v2);
  }
  unsigned short* dst = Wpk + (size_t)b * 4096 + tid * 8;
  *(u16x8*)dst = o1;
  *(u16x8*)(dst + 2048) = o2;
}

// ============== pack down_w -> bf16 k-major tiles, zero-pad k>=HID ======
__global__ __launch_bounds__(256) void pack_down(const float* __restrict__ down_w,
                                                 unsigned short* __restrict__ Wdk) {
  int b = blockIdx.x;            // (e*16+nt)*86 + kci
  int kci = b % KCD;
  int ent = b / KCD;
  int nt = ent & 15;
  int e = ent >> 4;
  int tid = threadIdx.x;
  int col = tid & 63, k0 = (tid >> 6) * 8;
  int n = nt * 64 + col;
  int kbase = kci * 32 + k0;
  const float* src = down_w + ((size_t)e * HID + kbase) * DM + n;
  u16x8 o;
#pragma unroll
  for (int j = 0; j < 8; j++) {
    float v = (kbase + j < HID) ? src[(size_t)j * DM] : 0.f;
    o[j] = f2bf(v);
  }
  *(u16x8*)(Wdk + (size_t)b * 2048 + tid * 8) = o;
}

// ============================ RMSNorm (bf16 out; optional fp32 out) ============================
template <bool F32OUT>
__global__ __launch_bounds__(256) void rms_kernel(const float* __restrict__ x,
                                                  const float* __restrict__ w,
                                                  float* __restrict__ out,
                                                  unsigned short* __restrict__ outb) {
  int row = blockIdx.x;
  int tid = threadIdx.x;
  const float4 v = ((const float4*)(x + (size_t)row * DM))[tid];
  float ss = v.x * v.x + v.y * v.y + v.z * v.z + v.w * v.w;
#pragma unroll
  for (int off = 32; off >= 1; off >>= 1) ss += __shfl_down(ss, off);
  __shared__ float red[4];
  if ((tid & 63) == 0) red[tid >> 6] = ss;
  __syncthreads();
  float tot = red[0] + red[1] + red[2] + red[3];
  float scale = rsqrtf(tot * (1.0f / 1024.0f) + 1e-5f);
  const float4 wv = ((const float4*)w)[tid];
  float4 o;
  o.x = v.x * scale * wv.x; o.y = v.y * scale * wv.y;
  o.z = v.z * scale * wv.z; o.w = v.w * scale * wv.w;
  if (F32OUT) ((float4*)(out + (size_t)row * DM))[tid] = o;
  ushort4 ob;
  ob.x = f2bf(o.x); ob.y = f2bf(o.y); ob.z = f2bf(o.z); ob.w = f2bf(o.w);
  *(ushort4*)(outb + (size_t)row * DM + tid * 4) = ob;
}

// ============================ dense bf16 MFMA GEMM ============================
// depth-3 gll staging, stage-ahead-2, 1 raw barrier/K-step, counted vmcnt(4).
template <bool BIAS, bool RES>
__global__ __launch_bounds__(256) void mfma_dense(const unsigned short* __restrict__ A,
                                                  const unsigned short* __restrict__ Bpk,
                                                  const float* __restrict__ bias,
                                                  const float* __restrict__ res,
                                                  float* __restrict__ C, int K, int N) {
  int m0 = blockIdx.x * 128;
  int n0 = blockIdx.y * 128;
  int KC = K >> 5;
  __shared__ unsigned short Asl[3][4096];   // 128 rows x 32k, chunk = lq*128+row
  __shared__ unsigned short Bsl[3][4096];   // 2 subtiles of 64col x 32k
  int tid = threadIdx.x;
  int l6 = tid & 63, wid = tid >> 6;
  int lr = l6 & 15, lq = l6 >> 4;
  int wm0 = (wid >> 1) * 64, wn0 = (wid & 1) * 64;
  int aw = wid * 512;
  f32x4 c[4][4];
  f32x4 zz = {0.f, 0.f, 0.f, 0.f};
#pragma unroll
  for (int i = 0; i < 4; i++)
#pragma unroll
    for (int j = 0; j < 4; j++) c[i][j] = zz;
  const unsigned short* aAg = A + (size_t)(m0 + (tid & 127)) * K + (tid >> 7) * 8;
  const unsigned short* bg0 = Bpk + (size_t)((n0 >> 6) * KC) * 2048 + tid * 8;
  const unsigned short* bg1 = Bpk + (size_t)(((n0 >> 6) + 1) * KC) * 2048 + tid * 8;
#define DEN_STG(buf, kci)                                       \
  {                                                             \
    gll16(aAg + (kci) * 32, &Asl[buf][aw]);                     \
    gll16(aAg + (kci) * 32 + 16, &Asl[buf][2048 + aw]);         \
    gll16(bg0 + (size_t)(kci) * 2048, &Bsl[buf][aw]);           \
    gll16(bg1 + (size_t)(kci) * 2048, &Bsl[buf][2048 + aw]);    \
  }
  DEN_STG(0, 0);
  DEN_STG(1, 1);
  VM_WAIT4;
  __builtin_amdgcn_s_barrier();
  CFENCE;
  int rb = 0, sb = 2;
  for (int kci = 0; kci < KC; kci++) {
    bf16x8 a[4], b[4];
#pragma unroll
    for (int mi = 0; mi < 4; mi++)
      a[mi] = *(bf16x8*)&Asl[rb][(lq * 128 + wm0 + mi * 16 + lr) * 8];
#pragma unroll
    for (int ni = 0; ni < 4; ni++)
      b[ni] = *(bf16x8*)&Bsl[rb][((wn0 >> 6) * 256 + lq * 64 + ni * 16 + lr) * 8];
    if (kci + 2 < KC) DEN_STG(sb, kci + 2);
    __builtin_amdgcn_s_setprio(1);
#pragma unroll
    for (int mi = 0; mi < 4; mi++)
#pragma unroll
      for (int ni = 0; ni < 4; ni++)
        c[mi][ni] = __builtin_amdgcn_mfma_f32_16x16x32_bf16(a[mi], b[ni], c[mi][ni], 0, 0, 0);
    __builtin_amdgcn_s_setprio(0);
    if (kci + 1 < KC) {
      if (kci + 2 < KC) { VM_WAIT4; } else { VM_WAIT0; }
      __builtin_amdgcn_s_barrier();
      CFENCE;
    }
    rb = (rb == 2) ? 0 : rb + 1;
    sb = (sb == 2) ? 0 : sb + 1;
  }
#undef DEN_STG
#pragma unroll
  for (int mi = 0; mi < 4; mi++)
#pragma unroll
    for (int ni = 0; ni < 4; ni++) {
      int nn = n0 + wn0 + ni * 16 + lr;
      float bv = BIAS ? bias[nn] : 0.f;
#pragma unroll
      for (int r = 0; r < 4; r++) {
        int mm = m0 + wm0 + mi * 16 + lq * 4 + r;
        float v = c[mi][ni][r] + bv;
        if (RES) v += res[(size_t)mm * N + nn];
        C[(size_t)mm * N + nn] = v;
      }
    }
}

// ============================ latent -> K,V expand (V out f16) ============================
__global__ void expand_kernel(const float* __restrict__ latents, const float* __restrict__ kb_w,
                              const float* __restrict__ vb_w, float* __restrict__ kpre,
                              _Float16* __restrict__ vf) {
  int idx = blockIdx.x * 256 + threadIdx.x;  // 4M
  int e = idx & 63;
  int t = (idx >> 6) & 1023;
  int h = (idx >> 16) & 15;
  int b = idx >> 20;
  const float* lrow = latents + ((size_t)(b * 1024 + t)) * DM;
  const float* kb = kb_w + (size_t)h * 2048;
  const float* vb = vb_w + (size_t)h * 2048;
  float ka = 0.f, va = 0.f;
#pragma unroll
  for (int l = 0; l < 32; l++) {
    ka += lrow[h * 32 + l] * kb[l * 64 + e];
    va += lrow[512 + h * 32 + l] * vb[l * 64 + e];
  }
  kpre[idx] = ka;
  vf[idx] = (_Float16)va;
}

// ============================ RoPE (out f16) ============================
template <bool IN_BTHD>
__global__ void rope_kernel(const float* __restrict__ in, _Float16* __restrict__ out) {
  int idx = blockIdx.x * 256 + threadIdx.x;  // 2M
  int i = idx & 31;
  int t = (idx >> 5) & 1023;
  int h = (idx >> 15) & 15;
  int b = idx >> 19;
  size_t ib;
  if (IN_BTHD)
    ib = ((size_t)(b * 1024 + t)) * DM + h * 64;
  else
    ib = ((size_t)((b * 16 + h) * 1024 + t)) * 64;
  float t1 = in[ib + 2 * i], t2 = in[ib + 2 * i + 1];
  float inv = exp2f(-(float)i * 0.41524101186091903f);  // 10000^(-i/32)
  float ang = (float)t * inv;
  float s, c;
  sincosf(ang, &s, &c);
  size_t ob = ((size_t)((b * 16 + h) * 1024 + t)) * 64;
  out[ob + i] = (_Float16)(t1 * c - t2 * s);
  out[ob + 32 + i] = (_Float16)(t1 * s + t2 * c);
}

// ============================ flash attention (f16 MFMA, bf16 out) ============================
__global__ __launch_bounds__(256) void attn_mfma(const _Float16* __restrict__ qf,
                                                 const _Float16* __restrict__ kf,
                                                 const _Float16* __restrict__ vf,
                                                 unsigned short* __restrict__ o) {
  __shared__ _Float16 Ks[64][72];
  __shared__ _Float16 Vt[64][68];
  int bh = blockIdx.y;
  int q0 = blockIdx.x * 64;
  int tid = threadIdx.x;
  int wv = tid >> 6, lane = tid & 63;
  int lr = lane & 15, lq = lane >> 4;
  const size_t base = (size_t)bh * 1024 * 64;
  const _Float16* qrow = qf + base + (size_t)(q0 + wv * 16 + lr) * 64;
  h16x8 qfr[2];
  qfr[0] = *(const h16x8*)(qrow + lq * 8);
  qfr[1] = *(const h16x8*)(qrow + 32 + lq * 8);
  float mrow = -3.0e38f, lsum = 0.f;
  f32x4 oacc[4];
  f32x4 zz = {0.f, 0.f, 0.f, 0.f};
#pragma unroll
  for (int i = 0; i < 4; i++) oacc[i] = zz;
  int skey = tid >> 2, spart = tid & 3;
  int vkey = tid & 63, vdb = (tid >> 6) * 16;

  for (int kt = 0; kt < 16; kt++) {
    __syncthreads();
    {
      const _Float16* kg = kf + base + (size_t)(kt * 64 + skey) * 64 + spart * 16;
      *(h16x8*)&Ks[skey][spart * 16] = *(const h16x8*)kg;
      *(h16x8*)&Ks[skey][spart * 16 + 8] = *(const h16x8*)(kg + 8);
      const _Float16* vg = vf + base + (size_t)(kt * 64 + vkey) * 64 + vdb;
      h16x8 v0 = *(const h16x8*)vg;
      h16x8 v1 = *(const h16x8*)(vg + 8);
#pragma unroll
      for (int j = 0; j < 8; j++) {
        Vt[vdb + j][vkey] = v0[j];
        Vt[vdb + 8 + j][vkey] = v1[j];
      }
    }
    __syncthreads();
    f32x4 st[4];
#pragma unroll
    for (int ni = 0; ni < 4; ni++) {
      st[ni] = zz;
#pragma unroll
      for (int kc = 0; kc < 2; kc++) {
        h16x8 ak = *(const h16x8*)&Ks[ni * 16 + lr][kc * 32 + lq * 8];
        st[ni] = __builtin_amdgcn_mfma_f32_16x16x32_f16(ak, qfr[kc], st[ni], 0, 0, 0);
      }
    }
    float smax = -3.0e38f;
#pragma unroll
    for (int ni = 0; ni < 4; ni++)
#pragma unroll
      for (int r = 0; r < 4; r++) {
        st[ni][r] *= 0.125f;
        smax = fmaxf(smax, st[ni][r]);
      }
    smax = fmaxf(smax, __shfl_xor(smax, 16));
    smax = fmaxf(smax, __shfl_xor(smax, 32));
    float newm = fmaxf(mrow, smax);
    float alpha = expf(mrow - newm);
    float rsum = 0.f;
    h16x4 pf[4];
#pragma unroll
    for (int ni = 0; ni < 4; ni++)
#pragma unroll
      for (int r = 0; r < 4; r++) {
        float p = expf(st[ni][r] - newm);
        rsum += p;
        pf[ni][r] = (_Float16)p;
      }
    rsum += __shfl_xor(rsum, 16);
    rsum += __shfl_xor(rsum, 32);
    lsum = lsum * alpha + rsum;
    mrow = newm;
#pragma unroll
    for (int dt = 0; dt < 4; dt++) {
      oacc[dt][0] *= alpha; oacc[dt][1] *= alpha;
      oacc[dt][2] *= alpha; oacc[dt][3] *= alpha;
    }
#pragma unroll
    for (int dt = 0; dt < 4; dt++)
#pragma unroll
      for (int ni = 0; ni < 4; ni++) {
        h16x4 va = *(const h16x4*)&Vt[dt * 16 + lr][ni * 16 + lq * 4];
        oacc[dt] = __builtin_amdgcn_mfma_f32_16x16x16f16(va, pf[ni], oacc[dt], 0, 0, 0);
      }
  }
  int b = bh >> 4, h = bh & 15;
  int qg = q0 + wv * 16 + lr;
  float invl = 1.0f / lsum;
  unsigned short* orow = o + (size_t)(b * 1024 + qg) * DM + h * 64;
#pragma unroll
  for (int dt = 0; dt < 4; dt++) {
    ushort4 ov;
    ov.x = f2bf(oacc[dt][0] * invl);
    ov.y = f2bf(oacc[dt][1] * invl);
    ov.z = f2bf(oacc[dt][2] * invl);
    ov.w = f2bf(oacc[dt][3] * invl);
    *(ushort4*)(orow + dt * 16 + lq * 4) = ov;
  }
}

// ============================ router ============================
__global__ __launch_bounds__(256) void router_kernel(
    const float* __restrict__ xn2, const float* __restrict__ route_w,
    const float* __restrict__ route_b, const float* __restrict__ noise_w,
    const float* __restrict__ noise_b, const float* __restrict__ noise_eps,
    int* __restrict__ topi, float* __restrict__ flat_p, float* __restrict__ probsum,
    int* __restrict__ slotmap) {
  int wave = threadIdx.x >> 6;
  int lane = threadIdx.x & 63;
  int tk = blockIdx.x * 4 + wave;
  float acc[8] = {0.f}, nacc[8] = {0.f};
  const float* xr = xn2 + (size_t)tk * DM;
  for (int it = 0; it < 16; it++) {
    int d = it * 64 + lane;
    float xv = xr[d];
    const float* rw = route_w + d * 8;
    const float* nw = noise_w + d * 8;
#pragma unroll
    for (int e = 0; e < 8; e++) {
      acc[e] += xv * rw[e];
      nacc[e] += xv * nw[e];
    }
  }
#pragma unroll
  for (int off = 32; off >= 1; off >>= 1) {
#pragma unroll
    for (int e = 0; e < 8; e++) {
      acc[e] += __shfl_down(acc[e], off);
      nacc[e] += __shfl_down(nacc[e], off);
    }
  }
  if (lane == 0) {
    float noisy[8];
#pragma unroll
    for (int e = 0; e < 8; e++) {
      float lg = acc[e] + route_b[e];
      float nl = nacc[e] + noise_b[e];
      float sp = (nl > 20.f) ? nl : log1pf(expf(nl));
      noisy[e] = lg + noise_eps[tk * 8 + e] * sp;
    }
    int i1 = 0;
    float n1 = noisy[0];
#pragma unroll
    for (int e = 1; e < 8; e++)
      if (noisy[e] > n1) { n1 = noisy[e]; i1 = e; }
    int i2 = -1;
    float n2 = -3.0e38f;
#pragma unroll
    for (int e = 0; e < 8; e++)
      if (e != i1 && noisy[e] > n2) { n2 = noisy[e]; i2 = e; }
    float r = expf(n2 - n1);
    float p1 = 1.0f / (1.0f + r);
    float p2 = r / (1.0f + r);
    topi[tk * 2] = i1;
    topi[tk * 2 + 1] = i2;
#pragma unroll
    for (int e = 0; e < 8; e++) flat_p[tk * 8 + e] = (e == i1) ? p1 : ((e == i2) ? p2 : 0.f);
    atomicAdd(&probsum[i1], p1);
    atomicAdd(&probsum[i2], p2);
    slotmap[tk * 2] = -1;
    slotmap[tk * 2 + 1] = -1;
  }
}

// ============================ capacity scan ============================
__global__ __launch_bounds__(512) void scan_kernel(const int* __restrict__ topi,
                                                   const float* __restrict__ flat_p,
                                                   int* __restrict__ tok, float* __restrict__ gate,
                                                   int* __restrict__ cnt, int* __restrict__ slotmap) {
  int e = threadIdx.x >> 6;
  int lane = threadIdx.x & 63;
  int count = 0;
  for (int base = 0; base < NTOK; base += 64) {
    int t = base + lane;
    int a = topi[t * 2], b = topi[t * 2 + 1];
    bool mflag = (a == e) || (b == e);
    unsigned long long mask = __ballot(mflag);
    int pos = count + __popcll(mask & ((1ull << lane) - 1ull));
    if (mflag && pos < CAP) {
      tok[e * CAP + pos] = t;
      gate[e * CAP + pos] = flat_p[t * 8 + e];
      int k = (a == e) ? 0 : 1;
      slotmap[t * 2 + k] = pos;
    }
    count += __popcll(mask);
  }
  if (lane == 0) cnt[e] = (count < CAP) ? count : CAP;
}

// ============================ expert GEMM 1: gathered xn2b @ Wpk, fused SiLU ============================
// XCD-pinned: e = L&7. depth-3 gll staging, counted vmcnt, 1 barrier/K-step.
__global__ __launch_bounds__(256) void mfma_swiglu(const unsigned short* __restrict__ xn2b,
                                                   const unsigned short* __restrict__ Wpk,
                                                   const int* __restrict__ tok,
                                                   const int* __restrict__ cnt,
                                                   unsigned short* __restrict__ ACT) {
  int L = blockIdx.x;
  int e = L & 7;
  int gw = L >> 3;
  int m0 = (gw & 7) * 128;
  int jt = gw >> 3;
  int j0 = jt * 64;
  __shared__ unsigned short Asl[3][4096];   // 128 x 32k
  __shared__ unsigned short B1sl[3][2048];  // 64 x 32k
  __shared__ unsigned short B2sl[3][2048];
  int tid = threadIdx.x;
  int l6 = tid & 63, wid = tid >> 6;
  int lr = l6 & 15, lq = l6 >> 4;
  int wm0 = (wid >> 1) * 64, wn0 = (wid & 1) * 32;
  int aw = wid * 512;
  int ce = cnt[e];
  int slot = m0 + (tid & 127);
  int tr = (slot < ce) ? tok[e * CAP + slot] : 0;
  const unsigned short* aAg = xn2b + (size_t)tr * DM + (tid >> 7) * 8;
  const unsigned short* wg = Wpk + (size_t)(e * 43 + jt) * 32 * 4096 + tid * 8;
  f32x4 c1[4][2], c2[4][2];
  f32x4 zz = {0.f, 0.f, 0.f, 0.f};
#pragma unroll
  for (int i = 0; i < 4; i++)
#pragma unroll
    for (int j = 0; j < 2; j++) { c1[i][j] = zz; c2[i][j] = zz; }
#define SWG_STG(buf, kci)                                        \
  {                                                              \
    gll16(aAg + (kci) * 32, &Asl[buf][aw]);                      \
    gll16(aAg + (kci) * 32 + 16, &Asl[buf][2048 + aw]);          \
    gll16(wg + (size_t)(kci) * 4096, &B1sl[buf][aw]);            \
    gll16(wg + (size_t)(kci) * 4096 + 2048, &B2sl[buf][aw]);     \
  }
  SWG_STG(0, 0);
  SWG_STG(1, 1);
  VM_WAIT4;
  __builtin_amdgcn_s_barrier();
  CFENCE;
  int rb = 0, sb = 2;
  for (int kci = 0; kci < 32; kci++) {
    bf16x8 a[4], b1[2], b2[2];
#pragma unroll
    for (int mi = 0; mi < 4; mi++)
      a[mi] = *(bf16x8*)&Asl[rb][(lq * 128 + wm0 + mi * 16 + lr) * 8];
#pragma unroll
    for (int ni = 0; ni < 2; ni++) {
      b1[ni] = *(bf16x8*)&B1sl[rb][(lq * 64 + wn0 + ni * 16 + lr) * 8];
      b2[ni] = *(bf16x8*)&B2sl[rb][(lq * 64 + wn0 + ni * 16 + lr) * 8];
    }
    if (kci + 2 < 32) SWG_STG(sb, kci + 2);
    __builtin_amdgcn_s_setprio(1);
#pragma unroll
    for (int mi = 0; mi < 4; mi++)
#pragma unroll
      for (int ni = 0; ni < 2; ni++) {
        c1[mi][ni] = __builtin_amdgcn_mfma_f32_16x16x32_bf16(a[mi], b1[ni], c1[mi][ni], 0, 0, 0);
        c2[mi][ni] = __builtin_amdgcn_mfma_f32_16x16x32_bf16(a[mi], b2[ni], c2[mi][ni], 0, 0, 0);
      }
    __builtin_amdgcn_s_setprio(0);
    if (kci + 1 < 32) {
      if (kci + 2 < 32) { VM_WAIT4; } else { VM_WAIT0; }
      __builtin_amdgcn_s_barrier();
      CFENCE;
    }
    rb = (rb == 2) ? 0 : rb + 1;
    sb = (sb == 2) ? 0 : sb + 1;
  }
#undef SWG_STG
#pragma unroll
  for (int mi = 0; mi < 4; mi++)
#pragma unroll
    for (int ni = 0; ni < 2; ni++)
#pragma unroll
      for (int r = 0; r < 4; r++) {
        int mm = m0 + wm0 + mi * 16 + lq * 4 + r;
        int cc = j0 + wn0 + ni * 16 + lr;
        float h1 = c1[mi][ni][r], h2 = c2[mi][ni][r];
        float act = (h1 / (1.0f + expf(-h1))) * h2;
        ACT[(size_t)e * CAP * HIDP + (size_t)mm * HIDP + cc] = f2bf(act);
      }
}

// ============================ expert GEMM 2: ACT @ Wdk -> OE fp32 ============================
// XCD-pinned by expert (e = L&7). depth-3 gll staging, counted vmcnt, 1 barrier/K-step.
__global__ __launch_bounds__(256) void mfma_down(const unsigned short* __restrict__ ACT,
                                                 const unsigned short* __restrict__ Wdk,
                                                 float* __restrict__ OE) {
  int L = blockIdx.x;
  int e = L & 7;
  int gw = L >> 3;
  int m0 = (gw & 7) * 128;
  int nt0 = (gw >> 3) * 2;
  int n0 = nt0 * 64;
  __shared__ unsigned short Asl[3][4096];
  __shared__ unsigned short Bsl[3][4096];
  int tid = threadIdx.x;
  int l6 = tid & 63, wid = tid >> 6;
  int lr = l6 & 15, lq = l6 >> 4;
  int wm0 = (wid >> 1) * 64, wn0 = (wid & 1) * 64;
  int aw = wid * 512;
  f32x4 c[4][4];
  f32x4 zz = {0.f, 0.f, 0.f, 0.f};
#pragma unroll
  for (int i = 0; i < 4; i++)
#pragma unroll
    for (int j = 0; j < 4; j++) c[i][j] = zz;
  const unsigned short* aAg =
      ACT + (size_t)e * CAP * HIDP + (size_t)(m0 + (tid & 127)) * HIDP + (tid >> 7) * 8;
  const unsigned short* bg0 = Wdk + ((size_t)(e * 16 + nt0) * KCD) * 2048 + tid * 8;
  const unsigned short* bg1 = Wdk + ((size_t)(e * 16 + nt0 + 1) * KCD) * 2048 + tid * 8;
#define DWN_STG(buf, kci)                                       \
  {                                                             \
    gll16(aAg + (kci) * 32, &Asl[buf][aw]);                     \
    gll16(aAg + (kci) * 32 + 16, &Asl[buf][2048 + aw]);         \
    gll16(bg0 + (size_t)(kci) * 2048, &Bsl[buf][aw]);           \
    gll16(bg1 + (size_t)(kci) * 2048, &Bsl[buf][2048 + aw]);    \
  }
  DWN_STG(0, 0);
  DWN_STG(1, 1);
  VM_WAIT4;
  __builtin_amdgcn_s_barrier();
  CFENCE;
  int rb = 0, sb = 2;
  for (int kci = 0; kci < KCD; kci++) {
    bf16x8 a[4], b[4];
#pragma unroll
    for (int mi = 0; mi < 4; mi++)
      a[mi] = *(bf16x8*)&Asl[rb][(lq * 128 + wm0 + mi * 16 + lr) * 8];
#pragma unroll
    for (int ni = 0; ni < 4; ni++)
      b[ni] = *(bf16x8*)&Bsl[rb][((wn0 >> 6) * 256 + lq * 64 + ni * 16 + lr) * 8];
    if (kci + 2 < KCD) DWN_STG(sb, kci + 2);
    __builtin_amdgcn_s_setprio(1);
#pragma unroll
    for (int mi = 0; mi < 4; mi++)
#pragma unroll
      for (int ni = 0; ni < 4; ni++)
        c[mi][ni] = __builtin_amdgcn_mfma_f32_16x16x32_bf16(a[mi], b[ni], c[mi][ni], 0, 0, 0);
    __builtin_amdgcn_s_setprio(0);
    if (kci + 1 < KCD) {
      if (kci + 2 < KCD) { VM_WAIT4; } else { VM_WAIT0; }
      __builtin_amdgcn_s_barrier();
      CFENCE;
    }
    rb = (rb == 2) ? 0 : rb + 1;
    sb = (sb == 2) ? 0 : sb + 1;
  }
#undef DWN_STG
#pragma unroll
  for (int mi = 0; mi < 4; mi++)
#pragma unroll
    for (int ni = 0; ni < 4; ni++)
#pragma unroll
      for (int r = 0; r < 4; r++) {
        int mm = m0 + wm0 + mi * 16 + lq * 4 + r;
        int nn = n0 + wn0 + ni * 16 + lr;
        OE[((size_t)e << 20) + (size_t)mm * DM + nn] = c[mi][ni][r];
      }
}

// ============================ combine ============================
__global__ void combine_kernel(const float* __restrict__ x2, const float* __restrict__ OE,
                               const int* __restrict__ topi, const int* __restrict__ slotmap,
                               const float* __restrict__ flat_p, float* __restrict__ out) {
  int idx = blockIdx.x * 256 + threadIdx.x;  // 1M float4s
  int t = idx >> 8;
  int c4 = (idx & 255) * 4;
  float4 v = *(const float4*)(x2 + (size_t)t * DM + c4);
#pragma unroll
  for (int k = 0; k < 2; k++) {
    int s = slotmap[t * 2 + k];
    if (s >= 0) {
      int e = topi[t * 2 + k];
      float g = flat_p[t * 8 + e];
      float4 ov = *(const float4*)(OE + ((size_t)e << 20) + (size_t)s * DM + c4);
      v.x += g * ov.x; v.y += g * ov.y; v.z += g * ov.z; v.w += g * ov.w;
    }
  }
  *(float4*)(out + (size_t)t * DM + c4) = v;
}

__global__ void aux_kernel(const float* __restrict__ probsum, float* __restrict__ out) {
  if (threadIdx.x == 0) {
    float s = 0.f;
#pragma unroll
    for (int e = 0; e < 8; e++) {
      float d = probsum[e] * (1.0f / 4096.0f) - 0.125f;
      s += d * d;
    }
    out[4194304] = s;
  }
}

// ============================ launch ============================
extern "C" void kernel_launch(void* const* d_in, const int* in_sizes, int n_in, void* d_out,
                              int out_size, void* d_ws, size_t ws_size, hipStream_t stream) {
  const float* x = (const float*)d_in[0];
  const float* noise_eps = (const float*)d_in[1];
  const float* ln1_w = (const float*)d_in[2];
  const float* ln2_w = (const float*)d_in[3];
  const float* q_w = (const float*)d_in[4];
  const float* q_b = (const float*)d_in[5];
  const float* ka_w = (const float*)d_in[6];
  const float* kb_w = (const float*)d_in[7];
  const float* va_w = (const float*)d_in[8];
  const float* vb_w = (const float*)d_in[9];
  const float* proj_w = (const float*)d_in[10];
  const float* proj_b = (const float*)d_in[11];
  const float* route_w = (const float*)d_in[12];
  const float* route_b = (const float*)d_in[13];
  const float* noise_w = (const float*)d_in[14];
  const float* noise_b = (const float*)d_in[15];
  const float* swiglu_w = (const float*)d_in[16];
  const float* down_w = (const float*)d_in[17];
  float* out = (float*)d_out;
  char* w = (char*)d_ws;
  const size_t MB = 1ull << 20;

  // ---- memory map (MiB), peak 171 ----
  // persistent: x2 [0,16) | xn2 [16,32) | xn2b [32,40) | sm [40,41)
  // phase A:   xnb [42,50) qtmp [50,66) latents [66,82) kpre [82,98) qfb [98,106)
  //            kfb [106,114) vfb [114,122) obb [122,130) Wqt [130,132) Wlatt [132,134) Wprojt [134,136)
  // after proj: Wpk [42,128)  (overlays dead phase-A buffers)
  // expert:    ACT [128,171)
  // after swiglu: Wdk [42,85) | OE [86,118)
  float* x2 = (float*)(w + 0 * MB);
  float* xn2 = (float*)(w + 16 * MB);
  unsigned short* xn2b = (unsigned short*)(w + 32 * MB);
  char* sm = w + 40 * MB;
  unsigned short* xnb = (unsigned short*)(w + 42 * MB);
  float* qtmp = (float*)(w + 50 * MB);
  float* latents = (float*)(w + 66 * MB);
  float* kpre = (float*)(w + 82 * MB);
  _Float16* qfb = (_Float16*)(w + 98 * MB);
  _Float16* kfb = (_Float16*)(w + 106 * MB);
  _Float16* vfb = (_Float16*)(w + 114 * MB);
  unsigned short* obb = (unsigned short*)(w + 122 * MB);
  unsigned short* Wqt = (unsigned short*)(w + 130 * MB);
  unsigned short* Wlatt = (unsigned short*)(w + 132 * MB);
  unsigned short* Wprojt = (unsigned short*)(w + 134 * MB);
  unsigned short* Wpk = (unsigned short*)(w + 42 * MB);
  unsigned short* ACT = (unsigned short*)(w + 128 * MB);
  unsigned short* Wdk = (unsigned short*)(w + 42 * MB);
  float* OE = (float*)(w + 86 * MB);

  int* topi = (int*)sm;
  int* tok = (int*)(sm + 64 * 1024);
  int* cntb = (int*)(sm + 128 * 1024);
  int* slotmap = (int*)(sm + 192 * 1024);
  float* flat_p = (float*)(sm + 256 * 1024);
  float* gateb = (float*)(sm + 512 * 1024);
  float* probsum = (float*)(sm + 576 * 1024);

  pack_dense3<<<1536, 256, 0, stream>>>(q_w, ka_w, va_w, proj_w, Wqt, Wlatt, Wprojt);
  rms_kernel<false><<<4096, 256, 0, stream>>>(x, ln1_w, nullptr, xnb);
  mfma_dense<true, false><<<dim3(32, 8), 256, 0, stream>>>(xnb, Wqt, q_b, nullptr, qtmp, 1024, 1024);
  mfma_dense<false, false><<<dim3(32, 8), 256, 0, stream>>>(xnb, Wlatt, nullptr, nullptr, latents, 1024, 1024);
  expand_kernel<<<16384, 256, 0, stream>>>(latents, kb_w, vb_w, kpre, vfb);
  rope_kernel<true><<<8192, 256, 0, stream>>>(qtmp, qfb);
  rope_kernel<false><<<8192, 256, 0, stream>>>(kpre, kfb);
  attn_mfma<<<dim3(16, 64), 256, 0, stream>>>(qfb, kfb, vfb, obb);
  mfma_dense<true, true><<<dim3(32, 8), 256, 0, stream>>>(obb, Wprojt, proj_b, x, x2, 1024, 1024);
  pack_swiglu<<<11008, 256, 0, stream>>>(swiglu_w, Wpk);
  rms_kernel<true><<<4096, 256, 0, stream>>>(x2, ln2_w, xn2, xn2b);
  hipMemsetAsync(probsum, 0, 8 * sizeof(float), stream);
  router_kernel<<<1024, 256, 0, stream>>>(xn2, route_w, route_b, noise_w, noise_b, noise_eps,
                                          topi, flat_p, probsum, slotmap);
  scan_kernel<<<1, 512, 0, stream>>>(topi, flat_p, tok, gateb, cntb, slotmap);
  mfma_swiglu<<<2752, 256, 0, stream>>>(xn2b, Wpk, tok, cntb, ACT);
  pack_down<<<11008, 256, 0, stream>>>(down_w, Wdk);
  mfma_down<<<512, 256, 0, stream>>>(ACT, Wdk, OE);
  combine_kernel<<<4096, 256, 0, stream>>>(x2, OE, topi, slotmap, flat_p, out);
  aux_kernel<<<1, 64, 0, stream>>>(probsum, out);
}